// Round 21
// baseline (406.296 us; speedup 1.0000x reference)
//
#include <hip/hip_runtime.h>
#include <hip/hip_bf16.h>

// ---------------------------------------------------------------------------
// Nystromformer attention.  (R21 = R19 core + NCH=16 pinv||s3v fusion.)
// Big GEMMs: PURE bf16 32x32x16 MFMA, 4-wave/128x128 2-barrier
// global_load_lds (R12-proven; R20's counted-vmcnt variant reverted).
// Attention pure bf16 (R14). Pinv fused with s3v (R18), NCH templated.
// Wide s2 + batched attn_out (R19).
// B=4, L=4096, D=1024, H=16, HD=64, NL=64, SEG=64, INV_ITERS=6
// ---------------------------------------------------------------------------

static constexpr int Bn  = 4;
static constexpr int Ln  = 4096;
static constexpr int Dn  = 1024;
static constexpr int Hn  = 16;
static constexpr int HDn = 64;
static constexpr int NLn = 64;
static constexpr int SEGn = 64;
static constexpr int BHn = Bn * Hn;     // 64
static constexpr int Mn  = Bn * Ln;     // 16384
#define NEG_BIG (-100000.0f)

// ---- workspace offsets (floats) ------------------------------------------
static constexpr size_t OFF_KT  = 0;          // Kt fp32; later attn packed
static constexpr size_t OFF_QT  = 16777216;
static constexpr size_t OFF_VT  = 33554432;   // Vt fp32; later wout packed
static constexpr size_t OFF_WOH = 33554432;   // 524288 fl (alias Vt)
static constexpr size_t OFF_WH  = 50331648;   // wkqv packed bf16, 1572864 fl
// smalls alias WH region (live only after kqv):
static constexpr size_t OFF_QLM = 50331648;
static constexpr size_t OFF_KLM = 50593792;
static constexpr size_t OFF_S2  = 50855936;
static constexpr size_t OFF_Z   = 51118080;
static constexpr size_t OFF_WM  = 51380224;
static constexpr size_t OFF_PM  = 51642368;   // 65536 (NCH<=16)
static constexpr size_t OFF_PS  = 51707904;   // 65536
static constexpr size_t OFF_GM  = 51773440;   // 64   (ends 51773504 < 51904512)
static constexpr size_t OFF_XS  = 53477376;   // x-slab packed ; Opart alias
static constexpr size_t OFF_PO  = 53477376;   // Opart: 64*NCH*4096 fl
// peak = OFF_XS + max(S*512, 64*NCH*4096) floats:
//   S=16384,NCH16 -> 236.0MB; S=8192,NCH16 -> 220.0MB; S=4096,NCH8 -> 212.0MB

using bf16x8 = __attribute__((ext_vector_type(8))) short;
using f32x16 = __attribute__((ext_vector_type(16))) float;
using s16x4  = __attribute__((ext_vector_type(4))) short;

__device__ __forceinline__ unsigned short f2bf(float f) {
    unsigned int u = __float_as_uint(f);
    return (unsigned short)((u + 0x7fffu + ((u >> 16) & 1u)) >> 16);
}
// 8 fp32 -> round-nearest bf16x8
__device__ __forceinline__ void cvt8r(const float* fs, bf16x8& hv) {
    #pragma unroll
    for (int e = 0; e < 8; ++e) hv[e] = (short)f2bf(fs[e]);
}
typedef __attribute__((address_space(1))) void gvoid;
typedef __attribute__((address_space(3))) void lvoid;
__device__ __forceinline__ void async16(void* l, const void* g) {
    __builtin_amdgcn_global_load_lds((gvoid*)(size_t)g, (lvoid*)l, 16, 0, 0);
}

// ---------------------------------------------------------------------------
// Pack: fp32 [row0.., 1024] -> round-nearest bf16, fragment-ordered 128x32
// tiles. Tile (rt,kt), slot s=(g*2+kk)*64+l : row=g*32+(l&31),
// k=kk*16+((l>>5)&1)*8+e.   (layout HW-verified R4-R20)
// ---------------------------------------------------------------------------
__global__ __launch_bounds__(256) void k_pack(
    const float* __restrict__ src, unsigned short* __restrict__ dh, int row0)
{
    __shared__ float Ls[128][33];
    const int rt = blockIdx.x, kt = blockIdx.y;
    const int tid = threadIdx.x;
    #pragma unroll
    for (int p = 0; p < 4; ++p) {
        const int row = p * 32 + (tid >> 3);
        const int c4 = (tid & 7) * 4;
        const float4 v = *(const float4*)&src[(size_t)(row0 + rt * 128 + row) * 1024 + kt * 32 + c4];
        Ls[row][c4 + 0] = v.x; Ls[row][c4 + 1] = v.y;
        Ls[row][c4 + 2] = v.z; Ls[row][c4 + 3] = v.w;
    }
    __syncthreads();
    const size_t tb = (size_t)(rt * 32 + kt) * 4096;
    for (int s = tid; s < 512; s += 256) {
        const int g = s >> 7, kk = (s >> 6) & 1, l = s & 63;
        const int row = g * 32 + (l & 31);
        const int k0 = kk * 16 + ((l >> 5) & 1) * 8;
        bf16x8 hv;
        cvt8r(&Ls[row][k0], hv);
        *(bf16x8*)&dh[tb + s * 8] = hv;
    }
}

// ---------------------------------------------------------------------------
// 4-wave pure-bf16 GEMM core (R12/R19-proven, 2-barrier, 16KB LDS).
// ---------------------------------------------------------------------------
#define GEMM4W_CORE(A_, B_, NNB)                                               \
    __shared__ __attribute__((aligned(16))) char smem[16384];                  \
    const int tid = threadIdx.x;                                               \
    const int lane = tid & 63, wid = tid >> 6;                                 \
    const int cpx = gridDim.x >> 3;                                            \
    const int wg = (blockIdx.x & 7) * cpx + (blockIdx.x >> 3);                 \
    const int bm = wg / (NNB), bn = wg % (NNB);                                \
    const int wrow = wid >> 1, wcol = wid & 1;                                 \
    const unsigned short* gsrc =                                               \
        (wid < 2 ? (A_) + (size_t)bm * 131072 : (B_) + (size_t)bn * 131072)    \
        + (wid & 1) * 2048 + lane * 8;                                         \
    char* ldst = smem + wid * 4096;                                            \
    f32x16 acc[2][2] = {};                                                     \
    for (int kt = 0; kt < 32; ++kt) {                                          \
        const unsigned short* g = gsrc + (size_t)kt * 4096;                    \
        __syncthreads();                                                       \
        _Pragma("unroll")                                                      \
        for (int i = 0; i < 4; ++i)                                            \
            async16(ldst + i * 1024, g + i * 512);                             \
        __syncthreads();                                                       \
        _Pragma("unroll")                                                      \
        for (int kk = 0; kk < 2; ++kk) {                                       \
            bf16x8 fa[2], fb[2];                                               \
            _Pragma("unroll")                                                  \
            for (int ti = 0; ti < 2; ++ti) {                                   \
                const int o = (((wrow * 2 + ti) * 2 + kk) << 10) + lane * 16;  \
                fa[ti] = *(const bf16x8*)(smem + o);                           \
            }                                                                  \
            _Pragma("unroll")                                                  \
            for (int tj = 0; tj < 2; ++tj) {                                   \
                const int o = (((wcol * 2 + tj) * 2 + kk) << 10) + lane * 16;  \
                fb[tj] = *(const bf16x8*)(smem + 8192 + o);                    \
            }                                                                  \
            _Pragma("unroll")                                                  \
            for (int ti = 0; ti < 2; ++ti)                                     \
                _Pragma("unroll")                                              \
                for (int tj = 0; tj < 2; ++tj)                                 \
                    acc[ti][tj] = __builtin_amdgcn_mfma_f32_32x32x16_bf16(     \
                        fa[ti], fb[tj], acc[ti][tj], 0, 0, 0);                 \
        }                                                                      \
    }

// K1: kqv GEMM, scatter to Kt/Qt/Vt with mask (+1/8 on Q).
__global__ __launch_bounds__(256) void k_kqv_gemm(
    const unsigned short* __restrict__ xh,
    const unsigned short* __restrict__ wh,
    const float* __restrict__ mask,
    float* __restrict__ Kt, float* __restrict__ Qt, float* __restrict__ Vt,
    int row0)
{
    GEMM4W_CORE(xh, wh, 24)
    const int part = bn >> 3;
    #pragma unroll
    for (int ti = 0; ti < 2; ++ti) {
        #pragma unroll
        for (int tj = 0; tj < 2; ++tj) {
            const int col = (bn * 128 + wcol * 64 + tj * 32 + (lane & 31)) & 1023;
            const int h = col >> 6, d = col & 63;
            #pragma unroll
            for (int r = 0; r < 16; ++r) {
                const int row = row0 + bm * 128 + wrow * 64 + ti * 32
                              + (r & 3) + 8 * (r >> 2) + 4 * (lane >> 5);
                const int b = row >> 12, l = row & 4095;
                const float mk = mask[b * Ln + l];
                const size_t idx = ((size_t)(b * Hn + h) * Ln + l) * HDn + d;
                const float v = acc[ti][tj][r] * mk;
                if (part == 0)      Kt[idx] = v;
                else if (part == 1) Qt[idx] = v * 0.125f;
                else                Vt[idx] = v;
            }
        }
    }
}

// K8: out GEMM + bias.
__global__ __launch_bounds__(256) void k_out_gemm(
    const unsigned short* __restrict__ ah_,
    const unsigned short* __restrict__ bh_,
    const float* __restrict__ bias, float* __restrict__ out)
{
    GEMM4W_CORE(ah_, bh_, 8)
    #pragma unroll
    for (int ti = 0; ti < 2; ++ti) {
        #pragma unroll
        for (int tj = 0; tj < 2; ++tj) {
            const int col = bn * 128 + wcol * 64 + tj * 32 + (lane & 31);
            const float bb = bias[col];
            #pragma unroll
            for (int r = 0; r < 16; ++r) {
                const int row = bm * 128 + wrow * 64 + ti * 32
                              + (r & 3) + 8 * (r >> 2) + 4 * (lane >> 5);
                out[(size_t)row * Dn + col] = acc[ti][tj][r] + bb;
            }
        }
    }
}

// ---------------------------------------------------------------------------
// K2: landmark means + zero gmax.
// ---------------------------------------------------------------------------
__global__ __launch_bounds__(64) void k_landmarks(
    const float* __restrict__ Kt, const float* __restrict__ Qt,
    const float* __restrict__ mask,
    float* __restrict__ klm, float* __restrict__ qlm, int* __restrict__ gmax)
{
    const int blk = blockIdx.x;
    const int m = blk & 63, bh = blk >> 6, b = bh >> 4;
    const int d = threadIdx.x;
    if (blk == 0 && d < 2) gmax[d] = 0;
    float mv = mask[b * Ln + m * SEGn + d];
    #pragma unroll
    for (int off = 32; off; off >>= 1) mv += __shfl_down(mv, off);
    const float denom = __shfl(mv, 0) + 1e-8f;
    const float* kp = Kt + ((size_t)bh * Ln + m * SEGn) * HDn + d;
    const float* qp = Qt + ((size_t)bh * Ln + m * SEGn) * HDn + d;
    float sk = 0.f, sq = 0.f;
    for (int j = 0; j < SEGn; ++j) {
        sk += kp[(size_t)j * HDn];
        sq += qp[(size_t)j * HDn];
    }
    klm[((size_t)bh * NLn + m) * HDn + d] = sk / denom;
    qlm[((size_t)bh * NLn + m) * HDn + d] = sq / denom;
}

// ---------------------------------------------------------------------------
// K3: s2 = softmax(q_lm @ k_lm^T) + global |row|/|col| sum maxes.
// (R19-proven wide version)
// ---------------------------------------------------------------------------
__global__ __launch_bounds__(256) void k_s2(
    const float* __restrict__ qlm, const float* __restrict__ klm,
    float* __restrict__ s2, int* __restrict__ gmax)
{
    const int bh = blockIdx.x;
    __shared__ float ql[64][65];
    __shared__ float kl[64][65];
    __shared__ float sr[64][65];
    __shared__ float red[64][4], red2[64][4];
    __shared__ float rtmp[64], ctmp[64];
    const int tid = threadIdx.x;
    for (int idx = tid; idx < 4096; idx += 256) {
        ql[idx >> 6][idx & 63] = qlm[(size_t)bh * 4096 + idx];
        kl[idx >> 6][idx & 63] = klm[(size_t)bh * 4096 + idx];
    }
    __syncthreads();
    const int row = tid >> 2, sg = tid & 3, c0 = sg * 16;
    float sv[16];
    float mx = -1e30f;
    #pragma unroll 4
    for (int m = 0; m < 16; ++m) {
        float s = 0.f;
        #pragma unroll 8
        for (int d2 = 0; d2 < 64; ++d2) s = fmaf(ql[row][d2], kl[c0 + m][d2], s);
        sv[m] = s;
        mx = fmaxf(mx, s);
    }
    red[row][sg] = mx;
    __syncthreads();
    mx = fmaxf(fmaxf(red[row][0], red[row][1]), fmaxf(red[row][2], red[row][3]));
    float sum = 0.f;
    #pragma unroll
    for (int m = 0; m < 16; ++m) {
        const float e = __expf(sv[m] - mx);
        sv[m] = e;
        sum += e;
    }
    red2[row][sg] = sum;
    __syncthreads();
    const float inv = 1.f / (red2[row][0] + red2[row][1] + red2[row][2] + red2[row][3]);
    float rs = 0.f;
    #pragma unroll
    for (int m = 0; m < 16; ++m) {
        const float v = sv[m] * inv;
        sr[row][c0 + m] = v;
        s2[(size_t)bh * 4096 + row * 64 + c0 + m] = v;
        rs += fabsf(v);
    }
    red[row][sg] = rs;
    __syncthreads();
    if (sg == 0)
        rtmp[row] = red[row][0] + red[row][1] + red[row][2] + red[row][3];
    float cs = 0.f;
    #pragma unroll
    for (int r = 0; r < 16; ++r) cs += fabsf(sr[c0 + r][row]);
    red2[row][sg] = cs;
    __syncthreads();
    if (sg == 0)
        ctmp[row] = red2[row][0] + red2[row][1] + red2[row][2] + red2[row][3];
    __syncthreads();
    if (tid < 64) {
        float rmax = rtmp[tid], cmax = ctmp[tid];
        #pragma unroll
        for (int off = 32; off; off >>= 1) {
            rmax = fmaxf(rmax, __shfl_down(rmax, off));
            cmax = fmaxf(cmax, __shfl_down(cmax, off));
        }
        if (tid == 0) {
            atomicMax(&gmax[0], __float_as_int(rmax));
            atomicMax(&gmax[1], __float_as_int(cmax));
        }
    }
}

// ---------------------------------------------------------------------------
// mm64v: 64x64 fp32 matmul, 256 threads, float4 LDS loads, 4x4 micro-tile.
// C = scl * A @ (SUB ? dg*I - B : B). Strides multiple of 4. (R13-proven)
// ---------------------------------------------------------------------------
template<int SUB>
__device__ __forceinline__ void mm64v(
    float* C, int ldc, const float* Ag, int lda,
    const float* Bm, int ldb, float dg, float scl)
{
    const int tid = threadIdx.x;
    const int tx = tid & 15, ty = tid >> 4;
    const int i0 = ty << 2, j0 = tx << 2;
    float acc[4][4] = {};
    for (int k0 = 0; k0 < 64; k0 += 4) {
        float4 a4[4], b4[4];
        #pragma unroll
        for (int i = 0; i < 4; ++i)
            a4[i] = *(const float4*)&Ag[(size_t)(i0 + i) * lda + k0];
        #pragma unroll
        for (int kk = 0; kk < 4; ++kk)
            b4[kk] = *(const float4*)&Bm[(size_t)(k0 + kk) * ldb + j0];
        if (SUB) {
            #pragma unroll
            for (int kk = 0; kk < 4; ++kk) {
                float* bp = (float*)&b4[kk];
                #pragma unroll
                for (int j = 0; j < 4; ++j)
                    bp[j] = ((k0 + kk == j0 + j) ? dg : 0.0f) - bp[j];
            }
        }
        #pragma unroll
        for (int i = 0; i < 4; ++i) {
            const float* ap = (const float*)&a4[i];
            #pragma unroll
            for (int kk = 0; kk < 4; ++kk) {
                const float* bp = (const float*)&b4[kk];
                #pragma unroll
                for (int j = 0; j < 4; ++j)
                    acc[i][j] = fmaf(ap[kk], bp[j], acc[i][j]);
            }
        }
    }
    __syncthreads();
    #pragma unroll
    for (int i = 0; i < 4; ++i)
        #pragma unroll
        for (int j = 0; j < 4; ++j) C[(size_t)(i0 + i) * ldc + j0 + j] = scl * acc[i][j];
    __syncthreads();
}

// ---------------------------------------------------------------------------
// K4+K5a FUSED, templated on chunk count: grid (BHn, NCH_+1).
//   blockIdx.y == NCH_ : pinv (R13 body); else s3v chunk (R14 body).
// ---------------------------------------------------------------------------
template<int NCH_>
__global__ __launch_bounds__(256) void k_pinv_s3v(
    const float* __restrict__ s2, const int* __restrict__ gmax,
    float* __restrict__ zout,
    const float* __restrict__ qlm, const float* __restrict__ Kt,
    const float* __restrict__ Vt, const float* __restrict__ mask,
    float* __restrict__ Opart, float* __restrict__ mpart, float* __restrict__ spart)
{
    __shared__ __attribute__((aligned(16))) char shm[61184];
    const int tid = threadIdx.x;

    if (blockIdx.y == NCH_) {
        float (*Zb)[68] = (float(*)[68])(shm);
        float (*XZ)[68] = (float(*)[68])(shm + 17408);
        float (*Tb)[68] = (float(*)[68])(shm + 34816);
        const int bh = blockIdx.x;
        const float* X = s2 + (size_t)bh * 4096;
        const float scale = 1.0f / (__int_as_float(gmax[0]) * __int_as_float(gmax[1]));
        for (int idx = tid; idx < 4096; idx += 256) {
            const int i = idx >> 6, j = idx & 63;
            Zb[i][j] = X[j * 64 + i] * scale;
        }
        __syncthreads();
        for (int it = 0; it < 6; ++it) {
            mm64v<0>(&XZ[0][0], 68, X, 64, &Zb[0][0], 68, 0.f, 1.f);
            mm64v<1>(&Tb[0][0], 68, &XZ[0][0], 68, &XZ[0][0], 68, 7.f, 1.f);
            mm64v<1>(&Tb[0][0], 68, &XZ[0][0], 68, &Tb[0][0], 68, 15.f, 1.f);
            mm64v<1>(&Zb[0][0], 68, &Zb[0][0], 68, &Tb[0][0], 68, 13.f, 0.25f);
        }
        for (int idx = tid; idx < 4096; idx += 256)
            zout[(size_t)bh * 4096 + idx] = Zb[idx >> 6][idx & 63];
        return;
    }

    float (*Sm)[65] = (float(*)[65])(shm);
    float (*Ks)[65] = (float(*)[65])(shm + 16640);
    float (*Vs)[65] = (float(*)[65])(shm + 33280);
    unsigned short* Qp = (unsigned short*)(shm + 49920);
    float (*red)[4]  = (float(*)[4])(shm + 58112);
    float (*red2)[4] = (float(*)[4])(shm + 59136);
    float* rowmax = (float*)(shm + 60160);
    float* rowsum = (float*)(shm + 60416);
    float* fac    = (float*)(shm + 60672);
    float* mrow   = (float*)(shm + 60928);
    const int bh = blockIdx.x, ch = blockIdx.y;
    const int b = bh >> 4;
    const int lane = tid & 63, wid = tid >> 6;
    const int wr = wid >> 1, wc = wid & 1;

    for (int idx = tid; idx < 4096; idx += 256)
        Sm[idx >> 6][idx & 63] = qlm[(size_t)bh * 4096 + idx];
    if (tid < 64) { rowmax[tid] = -1e30f; rowsum[tid] = 0.f; }
    __syncthreads();
    for (int s = tid; s < 512; s += 256) {
        const int g = s >> 8, kc = (s >> 6) & 3, l = s & 63;
        const int row = g * 32 + (l & 31);
        const int k0 = kc * 16 + ((l >> 5) & 1) * 8;
        bf16x8 hv;
        cvt8r(&Sm[row][k0], hv);
        *(bf16x8*)&Qp[s * 8] = hv;
    }
    f32x16 accO = {};
    const int t0beg = ch * (Ln / NCH_), t0end = t0beg + (Ln / NCH_);
    for (int t0 = t0beg; t0 < t0end; t0 += 64) {
        __syncthreads();
        for (int idx = tid; idx < 4096; idx += 256) {
            const int r = idx >> 6, c2 = idx & 63;
            Ks[r][c2] = Kt[((size_t)bh * Ln + t0 + r) * HDn + c2];
            Vs[r][c2] = Vt[((size_t)bh * Ln + t0 + r) * HDn + c2];
        }
        if (tid < 64) mrow[tid] = mask[b * Ln + t0 + tid];
        __syncthreads();
        f32x16 acc = {};
        #pragma unroll
        for (int kc = 0; kc < 4; ++kc) {
            const bf16x8 a_h = *(const bf16x8*)&Qp[((wr * 4 + kc) * 64 + lane) * 8];
            const int brow = wc * 32 + (lane & 31);
            const int k0 = kc * 16 + (lane >> 5) * 8;
            bf16x8 b_h;
            cvt8r(&Ks[brow][k0], b_h);
            acc = __builtin_amdgcn_mfma_f32_32x32x16_bf16(a_h, b_h, acc, 0, 0, 0);
        }
        #pragma unroll
        for (int r = 0; r < 16; ++r) {
            const int row = wr * 32 + (r & 3) + 8 * (r >> 2) + 4 * (lane >> 5);
            const int col = wc * 32 + (lane & 31);
            Sm[row][col] = acc[r] + (1.f - mrow[col]) * NEG_BIG;
        }
        __syncthreads();
        {
            const int row = tid >> 2, sg = tid & 3, c0 = sg * 16;
            float mx = -1e30f;
            #pragma unroll
            for (int c = 0; c < 16; ++c) mx = fmaxf(mx, Sm[row][c0 + c]);
            red[row][sg] = mx;
            __syncthreads();
            const float nm = fmaxf(rowmax[row],
                fmaxf(fmaxf(red[row][0], red[row][1]), fmaxf(red[row][2], red[row][3])));
            const float f = __expf(rowmax[row] - nm);
            float ps = 0.f;
            #pragma unroll
            for (int c = 0; c < 16; ++c) {
                const float e = __expf(Sm[row][c0 + c] - nm);
                Sm[row][c0 + c] = e;
                ps += e;
            }
            red2[row][sg] = ps;
            __syncthreads();
            if (sg == 0) {
                rowsum[row] = rowsum[row] * f
                    + red2[row][0] + red2[row][1] + red2[row][2] + red2[row][3];
                rowmax[row] = nm;
                fac[row] = f;
            }
        }
        __syncthreads();
        #pragma unroll
        for (int r = 0; r < 16; ++r) {
            const int row = wr * 32 + (r & 3) + 8 * (r >> 2) + 4 * (lane >> 5);
            accO[r] *= fac[row];
        }
        #pragma unroll
        for (int kc = 0; kc < 4; ++kc) {
            const int arow = wr * 32 + (lane & 31);
            const int ak0 = kc * 16 + (lane >> 5) * 8;
            bf16x8 a_h;
            cvt8r(&Sm[arow][ak0], a_h);
            const int bcol = wc * 32 + (lane & 31);
            const int bk0 = kc * 16 + (lane >> 5) * 8;
            float bw[8];
            #pragma unroll
            for (int e = 0; e < 8; ++e) bw[e] = Vs[bk0 + e][bcol];
            bf16x8 b_h;
            cvt8r(bw, b_h);
            accO = __builtin_amdgcn_mfma_f32_32x32x16_bf16(a_h, b_h, accO, 0, 0, 0);
        }
    }
    __syncthreads();
    #pragma unroll
    for (int r = 0; r < 16; ++r) {
        const int row = wr * 32 + (r & 3) + 8 * (r >> 2) + 4 * (lane >> 5);
        Vs[row][wc * 32 + (lane & 31)] = accO[r];
    }
    __syncthreads();
    const size_t ob = (size_t)(bh * NCH_ + ch) * 4096;
    for (int idx = tid; idx < 4096; idx += 256)
        Opart[ob + idx] = Vs[idx >> 6][idx & 63];
    if (tid < 64) {
        mpart[(bh * NCH_ + ch) * 64 + tid] = rowmax[tid];
        spart[(bh * NCH_ + ch) * 64 + tid] = rowsum[tid];
    }
}

// ---------------------------------------------------------------------------
// K5b+K6 fused, templated: merge chunks -> s3v (LDS) -> Wm = z_star @ s3v.
// ---------------------------------------------------------------------------
template<int NCH_>
__global__ __launch_bounds__(256) void k_mergez(
    const float* __restrict__ Opart, const float* __restrict__ mpart,
    const float* __restrict__ spart, const float* __restrict__ Zs,
    float* __restrict__ Wm)
{
    __shared__ float Sv[64][68];
    __shared__ float Zb[64][68];
    const int bh = blockIdx.x, tid = threadIdx.x;
    for (int idx = tid; idx < 4096; idx += 256)
        Zb[idx >> 6][idx & 63] = Zs[(size_t)bh * 4096 + idx];
    {
        const int r = tid >> 2, c0 = (tid & 3) * 16;
        float e[NCH_];
        float M = -1e30f;
        #pragma unroll
        for (int c = 0; c < NCH_; ++c) {
            e[c] = mpart[(bh * NCH_ + c) * 64 + r];
            M = fmaxf(M, e[c]);
        }
        float S = 0.f;
        #pragma unroll
        for (int c = 0; c < NCH_; ++c) {
            e[c] = __expf(e[c] - M);
            S += spart[(bh * NCH_ + c) * 64 + r] * e[c];
        }
        const float invS = 1.f / S;
        for (int col = c0; col < c0 + 16; ++col) {
            float o = 0.f;
            #pragma unroll
            for (int c = 0; c < NCH_; ++c)
                o += Opart[(size_t)(bh * NCH_ + c) * 4096 + r * 64 + col] * e[c];
            Sv[r][col] = o * invS;
        }
    }
    __syncthreads();
    const int tx = tid & 15, ty = tid >> 4;
    const int i0 = ty << 2, j0 = tx << 2;
    float acc[4][4] = {};
    for (int k0 = 0; k0 < 64; k0 += 4) {
        float4 a4[4], b4[4];
        #pragma unroll
        for (int i = 0; i < 4; ++i)
            a4[i] = *(const float4*)&Zb[i0 + i][k0];
        #pragma unroll
        for (int kk = 0; kk < 4; ++kk)
            b4[kk] = *(const float4*)&Sv[k0 + kk][j0];
        #pragma unroll
        for (int i = 0; i < 4; ++i) {
            const float* ap = (const float*)&a4[i];
            #pragma unroll
            for (int kk = 0; kk < 4; ++kk) {
                const float* bp = (const float*)&b4[kk];
                #pragma unroll
                for (int j = 0; j < 4; ++j)
                    acc[i][j] = fmaf(ap[kk], bp[j], acc[i][j]);
            }
        }
    }
    #pragma unroll
    for (int i = 0; i < 4; ++i)
        #pragma unroll
        for (int j = 0; j < 4; ++j)
            Wm[(size_t)bh * 4096 + (i0 + i) * 64 + j0 + j] = acc[i][j];
}

// ---------------------------------------------------------------------------
// K7: out_attn = softmax(q @ k_lm^T) @ W. (R19-proven: 4 Q-tiles per block)
// ---------------------------------------------------------------------------
__global__ __launch_bounds__(256) void k_attn_out(
    const float* __restrict__ Qt, const float* __restrict__ klm,
    const float* __restrict__ Wm, unsigned short* __restrict__ ah)
{
    const int lt0 = blockIdx.x * 4;
    const int bh = blockIdx.y;
    const int b = bh >> 4, h = bh & 15;
    __shared__ float Sm[64][65];
    __shared__ float Ks[64][65];
    __shared__ float Ws[64][65];
    __shared__ float Ob[64][65];
    __shared__ unsigned short Qp[4096];
    __shared__ float red[64][4], red2[64][4];
    __shared__ float invr[64];
    const int tid = threadIdx.x;
    const int lane = tid & 63, wid = tid >> 6;
    const int wr = wid >> 1, wc = wid & 1;

    for (int idx = tid; idx < 4096; idx += 256) {
        const int r = idx >> 6, c2 = idx & 63;
        Ks[r][c2] = klm[(size_t)bh * 4096 + idx];
        Ws[r][c2] = Wm[(size_t)bh * 4096 + idx];
    }
    __syncthreads();

    for (int sub = 0; sub < 4; ++sub) {
        const int lt = lt0 + sub;
        for (int idx = tid; idx < 4096; idx += 256)
            Sm[idx >> 6][idx & 63] = Qt[((size_t)bh * Ln + lt * 64 + (idx >> 6)) * HDn + (idx & 63)];
        __syncthreads();
        for (int s = tid; s < 512; s += 256) {
            const int g = s >> 8, kc = (s >> 6) & 3, l = s & 63;
            const int row = g * 32 + (l & 31);
            const int k0 = kc * 16 + ((l >> 5) & 1) * 8;
            bf16x8 hv;
            cvt8r(&Sm[row][k0], hv);
            *(bf16x8*)&Qp[s * 8] = hv;
        }
        __syncthreads();
        f32x16 acc = {};
        #pragma unroll
        for (int kc = 0; kc < 4; ++kc) {
            const bf16x8 a_h = *(const bf16x8*)&Qp[((wr * 4 + kc) * 64 + lane) * 8];
            const int brow = wc * 32 + (lane & 31);
            const int k0 = kc * 16 + (lane >> 5) * 8;
            bf16x8 b_h;
            cvt8r(&Ks[brow][k0], b_h);
            acc = __builtin_amdgcn_mfma_f32_32x32x16_bf16(a_h, b_h, acc, 0, 0, 0);
        }
        #pragma unroll
        for (int r = 0; r < 16; ++r) {
            const int row = wr * 32 + (r & 3) + 8 * (r >> 2) + 4 * (lane >> 5);
            Sm[row][wc * 32 + (lane & 31)] = acc[r];
        }
        __syncthreads();
        {
            const int row = tid >> 2, sg = tid & 3, c0 = sg * 16;
            float mx = -1e30f;
            #pragma unroll
            for (int c = 0; c < 16; ++c) mx = fmaxf(mx, Sm[row][c0 + c]);
            red[row][sg] = mx;
            __syncthreads();
            mx = fmaxf(fmaxf(red[row][0], red[row][1]), fmaxf(red[row][2], red[row][3]));
            float ps = 0.f;
            #pragma unroll
            for (int c = 0; c < 16; ++c) {
                const float e = __expf(Sm[row][c0 + c] - mx);
                Sm[row][c0 + c] = e;
                ps += e;
            }
            red2[row][sg] = ps;
            __syncthreads();
            if (sg == 0)
                invr[row] = 1.f / (red2[row][0] + red2[row][1] + red2[row][2] + red2[row][3]);
        }
        __syncthreads();
        f32x16 acc2 = {};
        #pragma unroll
        for (int kc = 0; kc < 4; ++kc) {
            const int arow = wr * 32 + (lane & 31);
            const int ak0 = kc * 16 + (lane >> 5) * 8;
            bf16x8 a_h;
            cvt8r(&Sm[arow][ak0], a_h);
            const int bcol = wc * 32 + (lane & 31);
            const int bk0 = kc * 16 + (lane >> 5) * 8;
            float bw[8];
            #pragma unroll
            for (int e = 0; e < 8; ++e) bw[e] = Ws[bk0 + e][bcol];
            bf16x8 b_h;
            cvt8r(bw, b_h);
            acc2 = __builtin_amdgcn_mfma_f32_32x32x16_bf16(a_h, b_h, acc2, 0, 0, 0);
        }
        __syncthreads();
        #pragma unroll
        for (int r = 0; r < 16; ++r) {
            const int row = wr * 32 + (r & 3) + 8 * (r >> 2) + 4 * (lane >> 5);
            Ob[row][wc * 32 + (lane & 31)] = acc2[r];
        }
        __syncthreads();
        {
            const int tx = tid & 15, ty = tid >> 4;
            const int i0 = ty << 2, j0 = tx << 2;
            const int kd = h * 64 + j0;
            const int kt2 = kd >> 5, kc2 = kd & 31;
            const int kk2 = kc2 >> 4, half = (kc2 & 15) >> 3, e0 = kc2 & 7;
            #pragma unroll
            for (int i = 0; i < 4; ++i) {
                const float inv = invr[i0 + i];
                const int gm = b * Ln + lt * 64 + i0 + i;
                const int mt = gm >> 7, g2 = (gm & 127) >> 5, lrow = gm & 31;
                const size_t u = (size_t)(mt * 32 + kt2) * 4096
                               + (size_t)(((g2 * 2 + kk2) * 64 + half * 32 + lrow) * 8 + e0);
                s16x4 hv;
                #pragma unroll
                for (int j = 0; j < 4; ++j)
                    hv[j] = (short)f2bf(Ob[i0 + i][j0 + j] * inv);
                *(s16x4*)&ah[u] = hv;
            }
        }
        __syncthreads();
    }
}

// ---------------------------------------------------------------------------
extern "C" void kernel_launch(void* const* d_in, const int* in_sizes, int n_in,
                              void* d_out, int out_size, void* d_ws, size_t ws_size,
                              hipStream_t stream)
{
    (void)in_sizes; (void)n_in; (void)out_size;
    const float* x    = (const float*)d_in[0];
    const float* mask = (const float*)d_in[1];
    const float* wkqv = (const float*)d_in[2];
    const float* wout = (const float*)d_in[3];
    const float* bout = (const float*)d_in[4];
    float* out = (float*)d_out;
    float* ws  = (float*)d_ws;

    float* Kt   = ws + OFF_KT;
    float* Qt   = ws + OFF_QT;
    float* Vt   = ws + OFF_VT;
    float* qlm  = ws + OFF_QLM;
    float* klm  = ws + OFF_KLM;
    float* s2   = ws + OFF_S2;
    float* zst  = ws + OFF_Z;
    float* Wm   = ws + OFF_WM;
    int*   gmax = (int*)(ws + OFF_GM);
    float* mpart = ws + OFF_PM;
    float* spart = ws + OFF_PS;
    float* Opart = ws + OFF_PO;                        // alias slab (dead)
    unsigned short* wh  = (unsigned short*)(ws + OFF_WH);
    unsigned short* woh = (unsigned short*)(ws + OFF_WOH);  // alias Vt (dead)
    unsigned short* attn_h = (unsigned short*)(ws + OFF_KT);

    // slab size + chunk count: S=16384/8192 fit Opart@NCH16 (64*16*4096 fl);
    // smallest map (212MB) only fits NCH8.
    int S = 2048, nch16 = 0;
    if (ws_size >= (size_t)(OFF_XS + 16384 * 512) * 4)      { S = 16384; nch16 = 1; }
    else if (ws_size >= (size_t)(OFF_XS + 8192 * 512) * 4)  { S = 8192;  nch16 = 1; }
    else if (ws_size >= (size_t)(OFF_XS + 2097152) * 4)     { S = 4096; }
    unsigned short* xhs = (unsigned short*)(ws + OFF_XS);

    k_pack<<<dim3(24, 32), 256, 0, stream>>>(wkqv, wh, 0);
    for (int s = 0; s < Mn / S; ++s) {
        k_pack<<<dim3(S / 128, 32), 256, 0, stream>>>(x, xhs, s * S);
        k_kqv_gemm<<<(S / 128) * 24, 256, 0, stream>>>(
            xhs, wh, mask, Kt, Qt, Vt, s * S);
    }
    k_landmarks<<<BHn * NLn, 64, 0, stream>>>(Kt, Qt, mask, klm, qlm, gmax);
    k_s2<<<BHn, 256, 0, stream>>>(qlm, klm, s2, gmax);
    if (nch16) {
        k_pinv_s3v<16><<<dim3(BHn, 17), 256, 0, stream>>>(
            s2, gmax, zst, qlm, Kt, Vt, mask, Opart, mpart, spart);
    } else {
        k_pinv_s3v<8><<<dim3(BHn, 9), 256, 0, stream>>>(
            s2, gmax, zst, qlm, Kt, Vt, mask, Opart, mpart, spart);
    }
    k_pack<<<dim3(8, 32), 256, 0, stream>>>(wout, woh, 0);
    if (nch16) {
        k_mergez<16><<<BHn, 256, 0, stream>>>(Opart, mpart, spart, zst, Wm);
    } else {
        k_mergez<8><<<BHn, 256, 0, stream>>>(Opart, mpart, spart, zst, Wm);
    }
    k_attn_out<<<dim3(Ln / 256, BHn), 256, 0, stream>>>(Qt, klm, Wm, attn_h);
    k_out_gemm<<<128 * 8, 256, 0, stream>>>(attn_h, woh, bout, out);
}

// Round 22
// 401.529 us; speedup vs baseline: 1.0119x; 1.0119x over previous
//
#include <hip/hip_runtime.h>
#include <hip/hip_bf16.h>

// ---------------------------------------------------------------------------
// Nystromformer attention.  (R22 = R19 best-known exact configuration.)
// Big GEMMs: PURE bf16 32x32x16 MFMA, 4-wave/128x128 2-barrier
// global_load_lds (R12-proven). Attention pure bf16 (R14). Pinv fused with
// s3v at NCH=8 (R18/R19-proven). Wide s2 + batched attn_out (R19).
// B=4, L=4096, D=1024, H=16, HD=64, NL=64, SEG=64, INV_ITERS=6
// ---------------------------------------------------------------------------

static constexpr int Bn  = 4;
static constexpr int Ln  = 4096;
static constexpr int Dn  = 1024;
static constexpr int Hn  = 16;
static constexpr int HDn = 64;
static constexpr int NLn = 64;
static constexpr int SEGn = 64;
static constexpr int BHn = Bn * Hn;     // 64
static constexpr int Mn  = Bn * Ln;     // 16384
static constexpr int NCH = 8;           // s3v chunks (R19-proven)
#define NEG_BIG (-100000.0f)

// ---- workspace offsets (floats) ------------------------------------------
static constexpr size_t OFF_KT  = 0;          // Kt fp32; later attn packed
static constexpr size_t OFF_QT  = 16777216;
static constexpr size_t OFF_VT  = 33554432;   // Vt fp32; later wout packed
static constexpr size_t OFF_WOH = 33554432;   // 524288 fl (alias Vt)
static constexpr size_t OFF_WH  = 50331648;   // wkqv packed bf16, 1572864 fl
// smalls alias WH region (live only after kqv):
static constexpr size_t OFF_QLM = 50331648;
static constexpr size_t OFF_KLM = 50593792;
static constexpr size_t OFF_S2  = 50855936;
static constexpr size_t OFF_Z   = 51118080;
static constexpr size_t OFF_WM  = 51380224;
static constexpr size_t OFF_PM  = 51642368;   // 32768
static constexpr size_t OFF_PS  = 51675136;   // 32768
static constexpr size_t OFF_GM  = 51707904;   // 64
static constexpr size_t OFF_XS  = 53477376;   // x-slab packed ; Opart alias
static constexpr size_t OFF_PO  = 53477376;   // Opart 2097152 fl
// peak = OFF_XS + max(S*512, 2097152) floats:
//   S=16384 -> 236.0MB, S=8192 -> 220.0MB, S<=4096 -> 212.0MB

using bf16x8 = __attribute__((ext_vector_type(8))) short;
using f32x16 = __attribute__((ext_vector_type(16))) float;
using s16x4  = __attribute__((ext_vector_type(4))) short;

__device__ __forceinline__ unsigned short f2bf(float f) {
    unsigned int u = __float_as_uint(f);
    return (unsigned short)((u + 0x7fffu + ((u >> 16) & 1u)) >> 16);
}
// 8 fp32 -> round-nearest bf16x8
__device__ __forceinline__ void cvt8r(const float* fs, bf16x8& hv) {
    #pragma unroll
    for (int e = 0; e < 8; ++e) hv[e] = (short)f2bf(fs[e]);
}
typedef __attribute__((address_space(1))) void gvoid;
typedef __attribute__((address_space(3))) void lvoid;
__device__ __forceinline__ void async16(void* l, const void* g) {
    __builtin_amdgcn_global_load_lds((gvoid*)(size_t)g, (lvoid*)l, 16, 0, 0);
}

// ---------------------------------------------------------------------------
// Pack: fp32 [row0.., 1024] -> round-nearest bf16, fragment-ordered 128x32
// tiles. Tile (rt,kt), slot s=(g*2+kk)*64+l : row=g*32+(l&31),
// k=kk*16+((l>>5)&1)*8+e.   (layout HW-verified R4-R21)
// ---------------------------------------------------------------------------
__global__ __launch_bounds__(256) void k_pack(
    const float* __restrict__ src, unsigned short* __restrict__ dh, int row0)
{
    __shared__ float Ls[128][33];
    const int rt = blockIdx.x, kt = blockIdx.y;
    const int tid = threadIdx.x;
    #pragma unroll
    for (int p = 0; p < 4; ++p) {
        const int row = p * 32 + (tid >> 3);
        const int c4 = (tid & 7) * 4;
        const float4 v = *(const float4*)&src[(size_t)(row0 + rt * 128 + row) * 1024 + kt * 32 + c4];
        Ls[row][c4 + 0] = v.x; Ls[row][c4 + 1] = v.y;
        Ls[row][c4 + 2] = v.z; Ls[row][c4 + 3] = v.w;
    }
    __syncthreads();
    const size_t tb = (size_t)(rt * 32 + kt) * 4096;
    for (int s = tid; s < 512; s += 256) {
        const int g = s >> 7, kk = (s >> 6) & 1, l = s & 63;
        const int row = g * 32 + (l & 31);
        const int k0 = kk * 16 + ((l >> 5) & 1) * 8;
        bf16x8 hv;
        cvt8r(&Ls[row][k0], hv);
        *(bf16x8*)&dh[tb + s * 8] = hv;
    }
}

// ---------------------------------------------------------------------------
// 4-wave pure-bf16 GEMM core (R12/R19-proven, 2-barrier, 16KB LDS).
// ---------------------------------------------------------------------------
#define GEMM4W_CORE(A_, B_, NNB)                                               \
    __shared__ __attribute__((aligned(16))) char smem[16384];                  \
    const int tid = threadIdx.x;                                               \
    const int lane = tid & 63, wid = tid >> 6;                                 \
    const int cpx = gridDim.x >> 3;                                            \
    const int wg = (blockIdx.x & 7) * cpx + (blockIdx.x >> 3);                 \
    const int bm = wg / (NNB), bn = wg % (NNB);                                \
    const int wrow = wid >> 1, wcol = wid & 1;                                 \
    const unsigned short* gsrc =                                               \
        (wid < 2 ? (A_) + (size_t)bm * 131072 : (B_) + (size_t)bn * 131072)    \
        + (wid & 1) * 2048 + lane * 8;                                         \
    char* ldst = smem + wid * 4096;                                            \
    f32x16 acc[2][2] = {};                                                     \
    for (int kt = 0; kt < 32; ++kt) {                                          \
        const unsigned short* g = gsrc + (size_t)kt * 4096;                    \
        __syncthreads();                                                       \
        _Pragma("unroll")                                                      \
        for (int i = 0; i < 4; ++i)                                            \
            async16(ldst + i * 1024, g + i * 512);                             \
        __syncthreads();                                                       \
        _Pragma("unroll")                                                      \
        for (int kk = 0; kk < 2; ++kk) {                                       \
            bf16x8 fa[2], fb[2];                                               \
            _Pragma("unroll")                                                  \
            for (int ti = 0; ti < 2; ++ti) {                                   \
                const int o = (((wrow * 2 + ti) * 2 + kk) << 10) + lane * 16;  \
                fa[ti] = *(const bf16x8*)(smem + o);                           \
            }                                                                  \
            _Pragma("unroll")                                                  \
            for (int tj = 0; tj < 2; ++tj) {                                   \
                const int o = (((wcol * 2 + tj) * 2 + kk) << 10) + lane * 16;  \
                fb[tj] = *(const bf16x8*)(smem + 8192 + o);                    \
            }                                                                  \
            _Pragma("unroll")                                                  \
            for (int ti = 0; ti < 2; ++ti)                                     \
                _Pragma("unroll")                                              \
                for (int tj = 0; tj < 2; ++tj)                                 \
                    acc[ti][tj] = __builtin_amdgcn_mfma_f32_32x32x16_bf16(     \
                        fa[ti], fb[tj], acc[ti][tj], 0, 0, 0);                 \
        }                                                                      \
    }

// K1: kqv GEMM, scatter to Kt/Qt/Vt with mask (+1/8 on Q).
__global__ __launch_bounds__(256) void k_kqv_gemm(
    const unsigned short* __restrict__ xh,
    const unsigned short* __restrict__ wh,
    const float* __restrict__ mask,
    float* __restrict__ Kt, float* __restrict__ Qt, float* __restrict__ Vt,
    int row0)
{
    GEMM4W_CORE(xh, wh, 24)
    const int part = bn >> 3;
    #pragma unroll
    for (int ti = 0; ti < 2; ++ti) {
        #pragma unroll
        for (int tj = 0; tj < 2; ++tj) {
            const int col = (bn * 128 + wcol * 64 + tj * 32 + (lane & 31)) & 1023;
            const int h = col >> 6, d = col & 63;
            #pragma unroll
            for (int r = 0; r < 16; ++r) {
                const int row = row0 + bm * 128 + wrow * 64 + ti * 32
                              + (r & 3) + 8 * (r >> 2) + 4 * (lane >> 5);
                const int b = row >> 12, l = row & 4095;
                const float mk = mask[b * Ln + l];
                const size_t idx = ((size_t)(b * Hn + h) * Ln + l) * HDn + d;
                const float v = acc[ti][tj][r] * mk;
                if (part == 0)      Kt[idx] = v;
                else if (part == 1) Qt[idx] = v * 0.125f;
                else                Vt[idx] = v;
            }
        }
    }
}

// K8: out GEMM + bias.
__global__ __launch_bounds__(256) void k_out_gemm(
    const unsigned short* __restrict__ ah_,
    const unsigned short* __restrict__ bh_,
    const float* __restrict__ bias, float* __restrict__ out)
{
    GEMM4W_CORE(ah_, bh_, 8)
    #pragma unroll
    for (int ti = 0; ti < 2; ++ti) {
        #pragma unroll
        for (int tj = 0; tj < 2; ++tj) {
            const int col = bn * 128 + wcol * 64 + tj * 32 + (lane & 31);
            const float bb = bias[col];
            #pragma unroll
            for (int r = 0; r < 16; ++r) {
                const int row = bm * 128 + wrow * 64 + ti * 32
                              + (r & 3) + 8 * (r >> 2) + 4 * (lane >> 5);
                out[(size_t)row * Dn + col] = acc[ti][tj][r] + bb;
            }
        }
    }
}

// ---------------------------------------------------------------------------
// K2: landmark means + zero gmax.
// ---------------------------------------------------------------------------
__global__ __launch_bounds__(64) void k_landmarks(
    const float* __restrict__ Kt, const float* __restrict__ Qt,
    const float* __restrict__ mask,
    float* __restrict__ klm, float* __restrict__ qlm, int* __restrict__ gmax)
{
    const int blk = blockIdx.x;
    const int m = blk & 63, bh = blk >> 6, b = bh >> 4;
    const int d = threadIdx.x;
    if (blk == 0 && d < 2) gmax[d] = 0;
    float mv = mask[b * Ln + m * SEGn + d];
    #pragma unroll
    for (int off = 32; off; off >>= 1) mv += __shfl_down(mv, off);
    const float denom = __shfl(mv, 0) + 1e-8f;
    const float* kp = Kt + ((size_t)bh * Ln + m * SEGn) * HDn + d;
    const float* qp = Qt + ((size_t)bh * Ln + m * SEGn) * HDn + d;
    float sk = 0.f, sq = 0.f;
    for (int j = 0; j < SEGn; ++j) {
        sk += kp[(size_t)j * HDn];
        sq += qp[(size_t)j * HDn];
    }
    klm[((size_t)bh * NLn + m) * HDn + d] = sk / denom;
    qlm[((size_t)bh * NLn + m) * HDn + d] = sq / denom;
}

// ---------------------------------------------------------------------------
// K3: s2 = softmax(q_lm @ k_lm^T) + global |row|/|col| sum maxes.
// (R19-proven wide version)
// ---------------------------------------------------------------------------
__global__ __launch_bounds__(256) void k_s2(
    const float* __restrict__ qlm, const float* __restrict__ klm,
    float* __restrict__ s2, int* __restrict__ gmax)
{
    const int bh = blockIdx.x;
    __shared__ float ql[64][65];
    __shared__ float kl[64][65];
    __shared__ float sr[64][65];
    __shared__ float red[64][4], red2[64][4];
    __shared__ float rtmp[64], ctmp[64];
    const int tid = threadIdx.x;
    for (int idx = tid; idx < 4096; idx += 256) {
        ql[idx >> 6][idx & 63] = qlm[(size_t)bh * 4096 + idx];
        kl[idx >> 6][idx & 63] = klm[(size_t)bh * 4096 + idx];
    }
    __syncthreads();
    const int row = tid >> 2, sg = tid & 3, c0 = sg * 16;
    float sv[16];
    float mx = -1e30f;
    #pragma unroll 4
    for (int m = 0; m < 16; ++m) {
        float s = 0.f;
        #pragma unroll 8
        for (int d2 = 0; d2 < 64; ++d2) s = fmaf(ql[row][d2], kl[c0 + m][d2], s);
        sv[m] = s;
        mx = fmaxf(mx, s);
    }
    red[row][sg] = mx;
    __syncthreads();
    mx = fmaxf(fmaxf(red[row][0], red[row][1]), fmaxf(red[row][2], red[row][3]));
    float sum = 0.f;
    #pragma unroll
    for (int m = 0; m < 16; ++m) {
        const float e = __expf(sv[m] - mx);
        sv[m] = e;
        sum += e;
    }
    red2[row][sg] = sum;
    __syncthreads();
    const float inv = 1.f / (red2[row][0] + red2[row][1] + red2[row][2] + red2[row][3]);
    float rs = 0.f;
    #pragma unroll
    for (int m = 0; m < 16; ++m) {
        const float v = sv[m] * inv;
        sr[row][c0 + m] = v;
        s2[(size_t)bh * 4096 + row * 64 + c0 + m] = v;
        rs += fabsf(v);
    }
    red[row][sg] = rs;
    __syncthreads();
    if (sg == 0)
        rtmp[row] = red[row][0] + red[row][1] + red[row][2] + red[row][3];
    float cs = 0.f;
    #pragma unroll
    for (int r = 0; r < 16; ++r) cs += fabsf(sr[c0 + r][row]);
    red2[row][sg] = cs;
    __syncthreads();
    if (sg == 0)
        ctmp[row] = red2[row][0] + red2[row][1] + red2[row][2] + red2[row][3];
    __syncthreads();
    if (tid < 64) {
        float rmax = rtmp[tid], cmax = ctmp[tid];
        #pragma unroll
        for (int off = 32; off; off >>= 1) {
            rmax = fmaxf(rmax, __shfl_down(rmax, off));
            cmax = fmaxf(cmax, __shfl_down(cmax, off));
        }
        if (tid == 0) {
            atomicMax(&gmax[0], __float_as_int(rmax));
            atomicMax(&gmax[1], __float_as_int(cmax));
        }
    }
}

// ---------------------------------------------------------------------------
// mm64v: 64x64 fp32 matmul, 256 threads, float4 LDS loads, 4x4 micro-tile.
// C = scl * A @ (SUB ? dg*I - B : B). Strides multiple of 4. (R13-proven)
// ---------------------------------------------------------------------------
template<int SUB>
__device__ __forceinline__ void mm64v(
    float* C, int ldc, const float* Ag, int lda,
    const float* Bm, int ldb, float dg, float scl)
{
    const int tid = threadIdx.x;
    const int tx = tid & 15, ty = tid >> 4;
    const int i0 = ty << 2, j0 = tx << 2;
    float acc[4][4] = {};
    for (int k0 = 0; k0 < 64; k0 += 4) {
        float4 a4[4], b4[4];
        #pragma unroll
        for (int i = 0; i < 4; ++i)
            a4[i] = *(const float4*)&Ag[(size_t)(i0 + i) * lda + k0];
        #pragma unroll
        for (int kk = 0; kk < 4; ++kk)
            b4[kk] = *(const float4*)&Bm[(size_t)(k0 + kk) * ldb + j0];
        if (SUB) {
            #pragma unroll
            for (int kk = 0; kk < 4; ++kk) {
                float* bp = (float*)&b4[kk];
                #pragma unroll
                for (int j = 0; j < 4; ++j)
                    bp[j] = ((k0 + kk == j0 + j) ? dg : 0.0f) - bp[j];
            }
        }
        #pragma unroll
        for (int i = 0; i < 4; ++i) {
            const float* ap = (const float*)&a4[i];
            #pragma unroll
            for (int kk = 0; kk < 4; ++kk) {
                const float* bp = (const float*)&b4[kk];
                #pragma unroll
                for (int j = 0; j < 4; ++j)
                    acc[i][j] = fmaf(ap[kk], bp[j], acc[i][j]);
            }
        }
    }
    __syncthreads();
    #pragma unroll
    for (int i = 0; i < 4; ++i)
        #pragma unroll
        for (int j = 0; j < 4; ++j) C[(size_t)(i0 + i) * ldc + j0 + j] = scl * acc[i][j];
    __syncthreads();
}

// ---------------------------------------------------------------------------
// K4+K5a FUSED (R18/R19-proven): grid (BHn, NCH+1).
// ---------------------------------------------------------------------------
__global__ __launch_bounds__(256) void k_pinv_s3v(
    const float* __restrict__ s2, const int* __restrict__ gmax,
    float* __restrict__ zout,
    const float* __restrict__ qlm, const float* __restrict__ Kt,
    const float* __restrict__ Vt, const float* __restrict__ mask,
    float* __restrict__ Opart, float* __restrict__ mpart, float* __restrict__ spart)
{
    __shared__ __attribute__((aligned(16))) char shm[61184];
    const int tid = threadIdx.x;

    if (blockIdx.y == NCH) {
        float (*Zb)[68] = (float(*)[68])(shm);
        float (*XZ)[68] = (float(*)[68])(shm + 17408);
        float (*Tb)[68] = (float(*)[68])(shm + 34816);
        const int bh = blockIdx.x;
        const float* X = s2 + (size_t)bh * 4096;
        const float scale = 1.0f / (__int_as_float(gmax[0]) * __int_as_float(gmax[1]));
        for (int idx = tid; idx < 4096; idx += 256) {
            const int i = idx >> 6, j = idx & 63;
            Zb[i][j] = X[j * 64 + i] * scale;
        }
        __syncthreads();
        for (int it = 0; it < 6; ++it) {
            mm64v<0>(&XZ[0][0], 68, X, 64, &Zb[0][0], 68, 0.f, 1.f);
            mm64v<1>(&Tb[0][0], 68, &XZ[0][0], 68, &XZ[0][0], 68, 7.f, 1.f);
            mm64v<1>(&Tb[0][0], 68, &XZ[0][0], 68, &Tb[0][0], 68, 15.f, 1.f);
            mm64v<1>(&Zb[0][0], 68, &Zb[0][0], 68, &Tb[0][0], 68, 13.f, 0.25f);
        }
        for (int idx = tid; idx < 4096; idx += 256)
            zout[(size_t)bh * 4096 + idx] = Zb[idx >> 6][idx & 63];
        return;
    }

    float (*Sm)[65] = (float(*)[65])(shm);
    float (*Ks)[65] = (float(*)[65])(shm + 16640);
    float (*Vs)[65] = (float(*)[65])(shm + 33280);
    unsigned short* Qp = (unsigned short*)(shm + 49920);
    float (*red)[4]  = (float(*)[4])(shm + 58112);
    float (*red2)[4] = (float(*)[4])(shm + 59136);
    float* rowmax = (float*)(shm + 60160);
    float* rowsum = (float*)(shm + 60416);
    float* fac    = (float*)(shm + 60672);
    float* mrow   = (float*)(shm + 60928);
    const int bh = blockIdx.x, ch = blockIdx.y;
    const int b = bh >> 4;
    const int lane = tid & 63, wid = tid >> 6;
    const int wr = wid >> 1, wc = wid & 1;

    for (int idx = tid; idx < 4096; idx += 256)
        Sm[idx >> 6][idx & 63] = qlm[(size_t)bh * 4096 + idx];
    if (tid < 64) { rowmax[tid] = -1e30f; rowsum[tid] = 0.f; }
    __syncthreads();
    for (int s = tid; s < 512; s += 256) {
        const int g = s >> 8, kc = (s >> 6) & 3, l = s & 63;
        const int row = g * 32 + (l & 31);
        const int k0 = kc * 16 + ((l >> 5) & 1) * 8;
        bf16x8 hv;
        cvt8r(&Sm[row][k0], hv);
        *(bf16x8*)&Qp[s * 8] = hv;
    }
    f32x16 accO = {};
    const int t0beg = ch * (Ln / NCH), t0end = t0beg + (Ln / NCH);
    for (int t0 = t0beg; t0 < t0end; t0 += 64) {
        __syncthreads();
        for (int idx = tid; idx < 4096; idx += 256) {
            const int r = idx >> 6, c2 = idx & 63;
            Ks[r][c2] = Kt[((size_t)bh * Ln + t0 + r) * HDn + c2];
            Vs[r][c2] = Vt[((size_t)bh * Ln + t0 + r) * HDn + c2];
        }
        if (tid < 64) mrow[tid] = mask[b * Ln + t0 + tid];
        __syncthreads();
        f32x16 acc = {};
        #pragma unroll
        for (int kc = 0; kc < 4; ++kc) {
            const bf16x8 a_h = *(const bf16x8*)&Qp[((wr * 4 + kc) * 64 + lane) * 8];
            const int brow = wc * 32 + (lane & 31);
            const int k0 = kc * 16 + (lane >> 5) * 8;
            bf16x8 b_h;
            cvt8r(&Ks[brow][k0], b_h);
            acc = __builtin_amdgcn_mfma_f32_32x32x16_bf16(a_h, b_h, acc, 0, 0, 0);
        }
        #pragma unroll
        for (int r = 0; r < 16; ++r) {
            const int row = wr * 32 + (r & 3) + 8 * (r >> 2) + 4 * (lane >> 5);
            const int col = wc * 32 + (lane & 31);
            Sm[row][col] = acc[r] + (1.f - mrow[col]) * NEG_BIG;
        }
        __syncthreads();
        {
            const int row = tid >> 2, sg = tid & 3, c0 = sg * 16;
            float mx = -1e30f;
            #pragma unroll
            for (int c = 0; c < 16; ++c) mx = fmaxf(mx, Sm[row][c0 + c]);
            red[row][sg] = mx;
            __syncthreads();
            const float nm = fmaxf(rowmax[row],
                fmaxf(fmaxf(red[row][0], red[row][1]), fmaxf(red[row][2], red[row][3])));
            const float f = __expf(rowmax[row] - nm);
            float ps = 0.f;
            #pragma unroll
            for (int c = 0; c < 16; ++c) {
                const float e = __expf(Sm[row][c0 + c] - nm);
                Sm[row][c0 + c] = e;
                ps += e;
            }
            red2[row][sg] = ps;
            __syncthreads();
            if (sg == 0) {
                rowsum[row] = rowsum[row] * f
                    + red2[row][0] + red2[row][1] + red2[row][2] + red2[row][3];
                rowmax[row] = nm;
                fac[row] = f;
            }
        }
        __syncthreads();
        #pragma unroll
        for (int r = 0; r < 16; ++r) {
            const int row = wr * 32 + (r & 3) + 8 * (r >> 2) + 4 * (lane >> 5);
            accO[r] *= fac[row];
        }
        #pragma unroll
        for (int kc = 0; kc < 4; ++kc) {
            const int arow = wr * 32 + (lane & 31);
            const int ak0 = kc * 16 + (lane >> 5) * 8;
            bf16x8 a_h;
            cvt8r(&Sm[arow][ak0], a_h);
            const int bcol = wc * 32 + (lane & 31);
            const int bk0 = kc * 16 + (lane >> 5) * 8;
            float bw[8];
            #pragma unroll
            for (int e = 0; e < 8; ++e) bw[e] = Vs[bk0 + e][bcol];
            bf16x8 b_h;
            cvt8r(bw, b_h);
            accO = __builtin_amdgcn_mfma_f32_32x32x16_bf16(a_h, b_h, accO, 0, 0, 0);
        }
    }
    __syncthreads();
    #pragma unroll
    for (int r = 0; r < 16; ++r) {
        const int row = wr * 32 + (r & 3) + 8 * (r >> 2) + 4 * (lane >> 5);
        Vs[row][wc * 32 + (lane & 31)] = accO[r];
    }
    __syncthreads();
    const size_t ob = (size_t)(bh * NCH + ch) * 4096;
    for (int idx = tid; idx < 4096; idx += 256)
        Opart[ob + idx] = Vs[idx >> 6][idx & 63];
    if (tid < 64) {
        mpart[(bh * NCH + ch) * 64 + tid] = rowmax[tid];
        spart[(bh * NCH + ch) * 64 + tid] = rowsum[tid];
    }
}

// ---------------------------------------------------------------------------
// K5b+K6 fused: merge chunks -> s3v (LDS only) -> Wm = z_star @ s3v.
// ---------------------------------------------------------------------------
__global__ __launch_bounds__(256) void k_mergez(
    const float* __restrict__ Opart, const float* __restrict__ mpart,
    const float* __restrict__ spart, const float* __restrict__ Zs,
    float* __restrict__ Wm)
{
    __shared__ float Sv[64][68];
    __shared__ float Zb[64][68];
    const int bh = blockIdx.x, tid = threadIdx.x;
    for (int idx = tid; idx < 4096; idx += 256)
        Zb[idx >> 6][idx & 63] = Zs[(size_t)bh * 4096 + idx];
    {
        const int r = tid >> 2, c0 = (tid & 3) * 16;
        float e[NCH];
        float M = -1e30f;
        #pragma unroll
        for (int c = 0; c < NCH; ++c) {
            e[c] = mpart[(bh * NCH + c) * 64 + r];
            M = fmaxf(M, e[c]);
        }
        float S = 0.f;
        #pragma unroll
        for (int c = 0; c < NCH; ++c) {
            e[c] = __expf(e[c] - M);
            S += spart[(bh * NCH + c) * 64 + r] * e[c];
        }
        const float invS = 1.f / S;
        for (int col = c0; col < c0 + 16; ++col) {
            float o = 0.f;
            #pragma unroll
            for (int c = 0; c < NCH; ++c)
                o += Opart[(size_t)(bh * NCH + c) * 4096 + r * 64 + col] * e[c];
            Sv[r][col] = o * invS;
        }
    }
    __syncthreads();
    const int tx = tid & 15, ty = tid >> 4;
    const int i0 = ty << 2, j0 = tx << 2;
    float acc[4][4] = {};
    for (int k0 = 0; k0 < 64; k0 += 4) {
        float4 a4[4], b4[4];
        #pragma unroll
        for (int i = 0; i < 4; ++i)
            a4[i] = *(const float4*)&Zb[i0 + i][k0];
        #pragma unroll
        for (int kk = 0; kk < 4; ++kk)
            b4[kk] = *(const float4*)&Sv[k0 + kk][j0];
        #pragma unroll
        for (int i = 0; i < 4; ++i) {
            const float* ap = (const float*)&a4[i];
            #pragma unroll
            for (int kk = 0; kk < 4; ++kk) {
                const float* bp = (const float*)&b4[kk];
                #pragma unroll
                for (int j = 0; j < 4; ++j)
                    acc[i][j] = fmaf(ap[kk], bp[j], acc[i][j]);
            }
        }
    }
    #pragma unroll
    for (int i = 0; i < 4; ++i)
        #pragma unroll
        for (int j = 0; j < 4; ++j)
            Wm[(size_t)bh * 4096 + (i0 + i) * 64 + j0 + j] = acc[i][j];
}

// ---------------------------------------------------------------------------
// K7: out_attn = softmax(q @ k_lm^T) @ W. (R19-proven: 4 Q-tiles per block)
// ---------------------------------------------------------------------------
__global__ __launch_bounds__(256) void k_attn_out(
    const float* __restrict__ Qt, const float* __restrict__ klm,
    const float* __restrict__ Wm, unsigned short* __restrict__ ah)
{
    const int lt0 = blockIdx.x * 4;
    const int bh = blockIdx.y;
    const int b = bh >> 4, h = bh & 15;
    __shared__ float Sm[64][65];
    __shared__ float Ks[64][65];
    __shared__ float Ws[64][65];
    __shared__ float Ob[64][65];
    __shared__ unsigned short Qp[4096];
    __shared__ float red[64][4], red2[64][4];
    __shared__ float invr[64];
    const int tid = threadIdx.x;
    const int lane = tid & 63, wid = tid >> 6;
    const int wr = wid >> 1, wc = wid & 1;

    for (int idx = tid; idx < 4096; idx += 256) {
        const int r = idx >> 6, c2 = idx & 63;
        Ks[r][c2] = klm[(size_t)bh * 4096 + idx];
        Ws[r][c2] = Wm[(size_t)bh * 4096 + idx];
    }
    __syncthreads();

    for (int sub = 0; sub < 4; ++sub) {
        const int lt = lt0 + sub;
        for (int idx = tid; idx < 4096; idx += 256)
            Sm[idx >> 6][idx & 63] = Qt[((size_t)bh * Ln + lt * 64 + (idx >> 6)) * HDn + (idx & 63)];
        __syncthreads();
        for (int s = tid; s < 512; s += 256) {
            const int g = s >> 8, kc = (s >> 6) & 3, l = s & 63;
            const int row = g * 32 + (l & 31);
            const int k0 = kc * 16 + ((l >> 5) & 1) * 8;
            bf16x8 hv;
            cvt8r(&Sm[row][k0], hv);
            *(bf16x8*)&Qp[s * 8] = hv;
        }
        __syncthreads();
        f32x16 acc = {};
        #pragma unroll
        for (int kc = 0; kc < 4; ++kc) {
            const bf16x8 a_h = *(const bf16x8*)&Qp[((wr * 4 + kc) * 64 + lane) * 8];
            const int brow = wc * 32 + (lane & 31);
            const int k0 = kc * 16 + (lane >> 5) * 8;
            bf16x8 b_h;
            cvt8r(&Ks[brow][k0], b_h);
            acc = __builtin_amdgcn_mfma_f32_32x32x16_bf16(a_h, b_h, acc, 0, 0, 0);
        }
        #pragma unroll
        for (int r = 0; r < 16; ++r) {
            const int row = wr * 32 + (r & 3) + 8 * (r >> 2) + 4 * (lane >> 5);
            Sm[row][wc * 32 + (lane & 31)] = acc[r];
        }
        __syncthreads();
        {
            const int row = tid >> 2, sg = tid & 3, c0 = sg * 16;
            float mx = -1e30f;
            #pragma unroll
            for (int c = 0; c < 16; ++c) mx = fmaxf(mx, Sm[row][c0 + c]);
            red[row][sg] = mx;
            __syncthreads();
            mx = fmaxf(fmaxf(red[row][0], red[row][1]), fmaxf(red[row][2], red[row][3]));
            float ps = 0.f;
            #pragma unroll
            for (int c = 0; c < 16; ++c) {
                const float e = __expf(Sm[row][c0 + c] - mx);
                Sm[row][c0 + c] = e;
                ps += e;
            }
            red2[row][sg] = ps;
            __syncthreads();
            if (sg == 0)
                invr[row] = 1.f / (red2[row][0] + red2[row][1] + red2[row][2] + red2[row][3]);
        }
        __syncthreads();
        f32x16 acc2 = {};
        #pragma unroll
        for (int kc = 0; kc < 4; ++kc) {
            const int arow = wr * 32 + (lane & 31);
            const int ak0 = kc * 16 + (lane >> 5) * 8;
            bf16x8 a_h;
            cvt8r(&Sm[arow][ak0], a_h);
            const int bcol = wc * 32 + (lane & 31);
            const int bk0 = kc * 16 + (lane >> 5) * 8;
            float bw[8];
            #pragma unroll
            for (int e = 0; e < 8; ++e) bw[e] = Ws[bk0 + e][bcol];
            bf16x8 b_h;
            cvt8r(bw, b_h);
            acc2 = __builtin_amdgcn_mfma_f32_32x32x16_bf16(a_h, b_h, acc2, 0, 0, 0);
        }
        __syncthreads();
        #pragma unroll
        for (int r = 0; r < 16; ++r) {
            const int row = wr * 32 + (r & 3) + 8 * (r >> 2) + 4 * (lane >> 5);
            Ob[row][wc * 32 + (lane & 31)] = acc2[r];
        }
        __syncthreads();
        {
            const int tx = tid & 15, ty = tid >> 4;
            const int i0 = ty << 2, j0 = tx << 2;
            const int kd = h * 64 + j0;
            const int kt2 = kd >> 5, kc2 = kd & 31;
            const int kk2 = kc2 >> 4, half = (kc2 & 15) >> 3, e0 = kc2 & 7;
            #pragma unroll
            for (int i = 0; i < 4; ++i) {
                const float inv = invr[i0 + i];
                const int gm = b * Ln + lt * 64 + i0 + i;
                const int mt = gm >> 7, g2 = (gm & 127) >> 5, lrow = gm & 31;
                const size_t u = (size_t)(mt * 32 + kt2) * 4096
                               + (size_t)(((g2 * 2 + kk2) * 64 + half * 32 + lrow) * 8 + e0);
                s16x4 hv;
                #pragma unroll
                for (int j = 0; j < 4; ++j)
                    hv[j] = (short)f2bf(Ob[i0 + i][j0 + j] * inv);
                *(s16x4*)&ah[u] = hv;
            }
        }
        __syncthreads();
    }
}

// ---------------------------------------------------------------------------
extern "C" void kernel_launch(void* const* d_in, const int* in_sizes, int n_in,
                              void* d_out, int out_size, void* d_ws, size_t ws_size,
                              hipStream_t stream)
{
    (void)in_sizes; (void)n_in; (void)out_size;
    const float* x    = (const float*)d_in[0];
    const float* mask = (const float*)d_in[1];
    const float* wkqv = (const float*)d_in[2];
    const float* wout = (const float*)d_in[3];
    const float* bout = (const float*)d_in[4];
    float* out = (float*)d_out;
    float* ws  = (float*)d_ws;

    float* Kt   = ws + OFF_KT;
    float* Qt   = ws + OFF_QT;
    float* Vt   = ws + OFF_VT;
    float* qlm  = ws + OFF_QLM;
    float* klm  = ws + OFF_KLM;
    float* s2   = ws + OFF_S2;
    float* zst  = ws + OFF_Z;
    float* Wm   = ws + OFF_WM;
    int*   gmax = (int*)(ws + OFF_GM);
    float* mpart = ws + OFF_PM;
    float* spart = ws + OFF_PS;
    float* Opart = ws + OFF_PO;                        // alias slab (dead)
    unsigned short* wh  = (unsigned short*)(ws + OFF_WH);
    unsigned short* woh = (unsigned short*)(ws + OFF_WOH);  // alias Vt (dead)
    unsigned short* attn_h = (unsigned short*)(ws + OFF_KT);

    // runtime slab size: largest S with (OFF_XS + max(S*512, 2097152))*4 <= ws_size
    int S = 2048;
    if (ws_size >= (size_t)(OFF_XS + 16384 * 512) * 4) S = 16384;
    else if (ws_size >= (size_t)(OFF_XS + 8192 * 512) * 4) S = 8192;
    else if (ws_size >= (size_t)(OFF_XS + 2097152) * 4) S = 4096;
    unsigned short* xhs = (unsigned short*)(ws + OFF_XS);

    k_pack<<<dim3(24, 32), 256, 0, stream>>>(wkqv, wh, 0);
    for (int s = 0; s < Mn / S; ++s) {
        k_pack<<<dim3(S / 128, 32), 256, 0, stream>>>(x, xhs, s * S);
        k_kqv_gemm<<<(S / 128) * 24, 256, 0, stream>>>(
            xhs, wh, mask, Kt, Qt, Vt, s * S);
    }
    k_landmarks<<<BHn * NLn, 64, 0, stream>>>(Kt, Qt, mask, klm, qlm, gmax);
    k_s2<<<BHn, 256, 0, stream>>>(qlm, klm, s2, gmax);
    k_pinv_s3v<<<dim3(BHn, NCH + 1), 256, 0, stream>>>(
        s2, gmax, zst, qlm, Kt, Vt, mask, Opart, mpart, spart);
    k_pack<<<dim3(8, 32), 256, 0, stream>>>(wout, woh, 0);
    k_mergez<<<BHn, 256, 0, stream>>>(Opart, mpart, spart, zst, Wm);
    k_attn_out<<<dim3(Ln / 256, BHn), 256, 0, stream>>>(Qt, klm, Wm, attn_h);
    k_out_gemm<<<128 * 8, 256, 0, stream>>>(attn_h, woh, bout, out);
}